// Round 14
// baseline (63.704 us; speedup 1.0000x reference)
//
#include <hip/hip_runtime.h>
#include <stdint.h>

#define K_TOP 300
#define C_CLS 80
#define CAND_M 1024
#define THRESH 2.6f
#define IOU_T 0.5f
#define HCAP 512          // candidates per half-image block

typedef unsigned long long u64;
typedef unsigned int u32;

__device__ __forceinline__ u32 f2key(float v) {
    u32 b = __float_as_uint(v);
    return (b & 0x80000000u) ? ~b : (b | 0x80000000u);
}
__device__ __forceinline__ float key2f(u32 k) {
    u32 b = (k & 0x80000000u) ? (k & 0x7FFFFFFFu) : ~k;
    return __uint_as_float(b);
}
__device__ __forceinline__ u64 shfl_xor64(u64 v, int m) {
    u32 lo = (u32)v, hi = (u32)(v >> 32);
    lo = __shfl_xor(lo, m, 64);
    hi = __shfl_xor(hi, m, 64);
    return ((u64)hi << 32) | lo;
}
__device__ __forceinline__ u64 cmpex(u64 v, u64 pv, bool lower, bool dir) {
    bool want_max = (lower == dir);
    bool gt = v > pv;
    return (want_max == gt) ? v : pv;
}

// ---- kernel 1: scan one half-image, collect candidates, sort 512 in-block ----
// (byte-identical to round 8: 512 threads, 4-deep load ILP, direction bit from
//  GLOBAL element index e = sub*512 + tid: sub0 run desc, sub1 asc)
__global__ __launch_bounds__(512)
void scan_sort_kernel(const float* __restrict__ logits,
                      u64* __restrict__ cand,
                      int N, int N4) {
    __shared__ u64 lbuf[HCAP];
    __shared__ u32 lcnt;
    const int img = blockIdx.x >> 1;
    const int sub = blockIdx.x & 1;
    const int tid = threadIdx.x;
    if (tid == 0) lcnt = 0;
    __syncthreads();

    const int half4 = N4 >> 1;
    const int start4 = sub * half4;
    const int count4 = (sub == 0) ? half4 : (N4 - half4);
    const float4* src = (const float4*)logits + (size_t)img * N4 + start4;
    const u32 idx0 = (u32)start4 << 2;

#define PROC4(v, iu)                                                              \
    {                                                                             \
        float xs[4] = {(v).x, (v).y, (v).z, (v).w};                               \
        _Pragma("unroll")                                                         \
        for (int s = 0; s < 4; ++s) {                                             \
            if (xs[s] > THRESH) {                                                 \
                u32 p = atomicAdd(&lcnt, 1u);                                     \
                if (p < HCAP)                                                     \
                    lbuf[p] = ((u64)f2key(xs[s]) << 32) |                         \
                              (u32)(0xFFFFFFFFu - (idx0 + ((u32)(iu) << 2) + s)); \
            }                                                                     \
        }                                                                         \
    }

    for (int i = tid; i < count4; i += 2048) {
        const int i1 = i + 512, i2 = i + 1024, i3 = i + 1536;
        const bool h1 = i1 < count4, h2 = i2 < count4, h3 = i3 < count4;
        float4 v0 = src[i];
        float4 v1{}, v2{}, v3{};
        if (h1) v1 = src[i1];
        if (h2) v2 = src[i2];
        if (h3) v3 = src[i3];
        PROC4(v0, i);
        if (h1) PROC4(v1, i1);
        if (h2) PROC4(v2, i2);
        if (h3) PROC4(v3, i3);
    }
#undef PROC4
    if (sub == 1) {
        const float* lg = logits + (size_t)img * N;
        for (int i = (N4 << 2) + tid; i < N; i += 512) {
            float x = lg[i];
            if (x > THRESH) {
                u32 p = atomicAdd(&lcnt, 1u);
                if (p < HCAP)
                    lbuf[p] = ((u64)f2key(x) << 32) | (u32)(0xFFFFFFFFu - (u32)i);
            }
        }
    }
    __syncthreads();
    u32 n = lcnt;
    if (n > HCAP) n = HCAP;
    u64 r = ((u32)tid < n) ? lbuf[tid] : 0ull;
    __syncthreads();

    const unsigned e = ((unsigned)sub << 9) | (unsigned)tid;
    for (unsigned k = 2; k <= 512; k <<= 1) {
        const bool dir = ((e & k) == 0);
        for (unsigned j = k >> 1; j >= 64; j >>= 1) {
            lbuf[tid] = r;
            __syncthreads();
            u64 p = lbuf[tid ^ j];
            __syncthreads();
            r = cmpex(r, p, (tid & j) == 0, dir);
        }
        unsigned js = ((k >> 1) > 32u) ? 32u : (k >> 1);
        for (unsigned j = js; j >= 1; j >>= 1) {
            u64 p = shfl_xor64(r, (int)j);
            r = cmpex(r, p, (tid & j) == 0, dir);
        }
    }
    cand[(size_t)img * CAND_M + e] = r;
}

// ---- kernel 2: k=1024 bitonic merge + decode/outputs + mask build + greedy ----
// (round-8 structure; deletions only: no sar array, no smask zero-init,
//  float4 box store)
__global__ __launch_bounds__(1024)
void nms_fused_kernel(const u64* __restrict__ candg,
                      const float* __restrict__ boxes,
                      const int* __restrict__ sizes,
                      float* __restrict__ out,
                      int B, int Q, int C) {
    const int b = blockIdx.x;
    const int tid = threadIdx.x;
    const int BK = B * K_TOP;

    __shared__ u64 sLds[CAND_M];
    __shared__ float4 sbox[K_TOP];
    __shared__ u64 smask[K_TOP * 5];   // row-major [i*5 + w]; only w <= i>>6 valid
    __shared__ u64 skw[5];

    u64 r = candg[(size_t)b * CAND_M + tid];

    // final bitonic merge, k=1024, descending
    for (unsigned j = 512; j >= 64; j >>= 1) {
        sLds[tid] = r;
        __syncthreads();
        u64 p = sLds[tid ^ j];
        __syncthreads();
        r = cmpex(r, p, (tid & j) == 0, true);
    }
    for (unsigned j = 32; j >= 1; j >>= 1) {
        u64 p = shfl_xor64(r, (int)j);
        r = cmpex(r, p, (tid & j) == 0, true);
    }
    // thread tid holds sorted element tid

    // decode + outputs (valid <=> key != 0; real keys always have top bit set)
    if (tid < K_TOP) {
        const int valid = ((u32)(r >> 32)) != 0u;
        const float s0 = (float)sizes[b * 2 + 0];
        const float s1 = (float)sizes[b * 2 + 1];
        u32 key = (u32)(r >> 32);
        u32 idx = 0xFFFFFFFFu - (u32)(r & 0xFFFFFFFFull);
        if (!valid) idx = 0;
        float v = key2f(key);
        float score = valid ? (1.0f / (1.0f + expf(-v))) : 0.0f;
        int q = (int)(idx / (u32)C);
        int lab = (int)idx - q * C;
        float4 bx = ((const float4*)(boxes + ((size_t)b * Q + q) * 4))[0];
        float x1 = (bx.x - 0.5f * bx.z) * s0;
        float y1 = (bx.y - 0.5f * bx.w) * s1;
        float x2 = (bx.x + 0.5f * bx.z) * s0;
        float y2 = (bx.y + 0.5f * bx.w) * s1;
        if (!valid) { x1 = y1 = x2 = y2 = 0.0f; lab = 0; }
        out[(size_t)b * K_TOP + tid] = (float)lab;
        float4* ob = (float4*)(out + BK + ((size_t)b * K_TOP + tid) * 4);
        *ob = make_float4(x1, y1, x2, y2);
        out[(size_t)BK * 5 + (size_t)b * K_TOP + tid] = score;
        sbox[tid] = make_float4(x1, y1, x2, y2);
    }
    __syncthreads();

    // NMS bitmasks: 15 wave-tiles (row-group rg, word w), w <= rg.
    // Areas recomputed from box registers (bit-identical to (x2-x1)*(y2-y1));
    // inner loop does ONE LDS broadcast read (b128) per j.
    {
        const int wv = tid >> 6;
        const int lane = tid & 63;
        if (wv < 15) {
            const int rtab[15] = {0,1,1,2,2,2,3,3,3,3,4,4,4,4,4};
            const int wtab[15] = {0,0,1,0,1,2,0,1,2,3,0,1,2,3,4};
            const int rg = rtab[wv];
            const int w  = wtab[wv];
            const int i  = rg * 64 + lane;
            const int ic = (i < K_TOP) ? i : (K_TOP - 1);
            float4 bi = sbox[ic];
            float ai = (bi.z - bi.x) * (bi.w - bi.y);
            const int jbase = w << 6;
            int jend = K_TOP - jbase;
            if (jend > 64) jend = 64;
            u64 m = 0ull;
            for (int jj = 0; jj < jend; ++jj) {
                int j = jbase + jj;          // uniform -> LDS broadcast
                float4 bj = sbox[j];
                float aj = (bj.z - bj.x) * (bj.w - bj.y);
                float xx1 = fmaxf(bi.x, bj.x);
                float yy1 = fmaxf(bi.y, bj.y);
                float xx2 = fminf(bi.z, bj.z);
                float yy2 = fminf(bi.w, bj.w);
                float ww = fmaxf(xx2 - xx1, 0.0f);
                float hh = fmaxf(yy2 - yy1, 0.0f);
                float inter = ww * hh;
                float iou = inter / (ai + aj - inter + 1e-9f);
                if (iou > IOU_T && j < i) m |= (1ull << jj);
            }
            if (i < K_TOP) smask[i * 5 + w] = m;
        }
    }
    __syncthreads();

    // greedy scan, pipelined 4-row lookahead (wave 0). Words above the
    // diagonal (lane > row>>6) are never written -> masked at load
    // (verified correct in round 13).
    if (tid < 64) {
        const int lane = tid;
        const bool act = (lane < 5);
        u64 kw = 0ull;
#define LDM(row) ((act && (row) < K_TOP && lane <= ((row) >> 6)) \
                      ? smask[(row) * 5 + lane] : 0ull)
#define GSTEP(mrow, ii)                                                   \
        {                                                                 \
            u64 part = (mrow) & kw;                                       \
            bool sup = (__ballot(part != 0ull) != 0ull);                  \
            if (!sup && lane == ((ii) >> 6)) kw |= (1ull << ((ii) & 63)); \
        }
        u64 n0 = LDM(0), n1 = LDM(1), n2 = LDM(2), n3 = LDM(3);
        for (int c = 0; c < K_TOP / 4; ++c) {
            const int base = c * 4;
            u64 p0 = LDM(base + 4);
            u64 p1 = LDM(base + 5);
            u64 p2 = LDM(base + 6);
            u64 p3 = LDM(base + 7);
            GSTEP(n0, base + 0);
            GSTEP(n1, base + 1);
            GSTEP(n2, base + 2);
            GSTEP(n3, base + 3);
            n0 = p0; n1 = p1; n2 = p2; n3 = p3;
        }
#undef LDM
#undef GSTEP
        if (act) skw[lane] = kw;
    }
    __syncthreads();
    if (tid < K_TOP) {
        u32 keep = (u32)((skw[tid >> 6] >> (tid & 63)) & 1ull);
        out[(size_t)BK * 6 + (size_t)b * K_TOP + tid] = (float)keep;
    }
}

// ---------------- fallback monolithic (proven round-1) ----------------

__global__ __launch_bounds__(1024)
void rtdetr_post_kernel(const float* __restrict__ logits,
                        const float* __restrict__ boxes,
                        const int* __restrict__ sizes,
                        float* __restrict__ out,
                        int B, int Q, int C) {
    const int b = blockIdx.x;
    const int tid = threadIdx.x;
    const int bd = blockDim.x;
    const int N = Q * C;
    const int BK = B * K_TOP;

    __shared__ u64 cand[CAND_M];
    __shared__ u32 s_ncand;
    __shared__ float sb[K_TOP][4];
    __shared__ float sarea[K_TOP];
    __shared__ u64 smask[K_TOP * 5];
    __shared__ float skeep[K_TOP];

    if (tid == 0) s_ncand = 0;
    __syncthreads();

    const float* lg = logits + (size_t)b * N;
    const int nv = N >> 2;
    const float4* lg4 = (const float4*)lg;
    for (int i = tid; i < nv; i += bd) {
        float4 v = lg4[i];
        const int base = i * 4;
        float xs[4] = {v.x, v.y, v.z, v.w};
#pragma unroll
        for (int s = 0; s < 4; ++s) {
            float x = xs[s];
            if (x > THRESH) {
                u32 pos = atomicAdd(&s_ncand, 1u);
                if (pos < CAND_M)
                    cand[pos] = ((u64)f2key(x) << 32) | (u32)(0xFFFFFFFFu - (u32)(base + s));
            }
        }
    }
    __syncthreads();
    u32 ncand = s_ncand;
    if (ncand > CAND_M) ncand = CAND_M;
    for (int i = tid; i < CAND_M; i += bd)
        if (i >= (int)ncand) cand[i] = 0ull;
    __syncthreads();

    for (unsigned k = 2; k <= CAND_M; k <<= 1) {
        for (unsigned j = k >> 1; j > 0; j >>= 1) {
            for (unsigned t = tid; t < CAND_M; t += bd) {
                unsigned ixj = t ^ j;
                if (ixj > t) {
                    u64 a = cand[t], bb = cand[ixj];
                    bool sw = ((t & k) == 0) ? (a < bb) : (a > bb);
                    if (sw) { cand[t] = bb; cand[ixj] = a; }
                }
            }
            __syncthreads();
        }
    }

    const float s0 = (float)sizes[b * 2 + 0];
    const float s1 = (float)sizes[b * 2 + 1];
    if (tid < K_TOP) {
        u64 e = cand[tid];
        const int valid = (tid < (int)ncand);
        u32 key = (u32)(e >> 32);
        u32 idx = 0xFFFFFFFFu - (u32)(e & 0xFFFFFFFFull);
        if (!valid) idx = 0;
        float v = key2f(key);
        float score = valid ? (1.0f / (1.0f + expf(-v))) : 0.0f;
        int q = (int)(idx / (u32)C);
        int lab = (int)idx - q * C;
        float4 bx = ((const float4*)(boxes + ((size_t)b * Q + q) * 4))[0];
        float x1 = (bx.x - 0.5f * bx.z) * s0;
        float y1 = (bx.y - 0.5f * bx.w) * s1;
        float x2 = (bx.x + 0.5f * bx.z) * s0;
        float y2 = (bx.y + 0.5f * bx.w) * s1;
        if (!valid) { x1 = y1 = x2 = y2 = 0.0f; lab = 0; }
        out[(size_t)b * K_TOP + tid] = (float)lab;
        float* ob = out + BK + ((size_t)b * K_TOP + tid) * 4;
        ob[0] = x1; ob[1] = y1; ob[2] = x2; ob[3] = y2;
        out[(size_t)BK * 5 + (size_t)b * K_TOP + tid] = score;
        sb[tid][0] = x1; sb[tid][1] = y1; sb[tid][2] = x2; sb[tid][3] = y2;
        sarea[tid] = (x2 - x1) * (y2 - y1);
    }
    __syncthreads();

    for (int task = tid; task < K_TOP * 5; task += bd) {
        int i = task / 5;
        int w = task - i * 5;
        int jbase = w * 64;
        u64 m = 0ull;
        int jend = i - jbase;
        if (jend > 64) jend = 64;
        if (jend > 0) {
            float xi1 = sb[i][0], yi1 = sb[i][1], xi2 = sb[i][2], yi2 = sb[i][3];
            float ai = sarea[i];
            for (int jj = 0; jj < jend; ++jj) {
                int j = jbase + jj;
                float xx1 = fmaxf(xi1, sb[j][0]);
                float yy1 = fmaxf(yi1, sb[j][1]);
                float xx2 = fminf(xi2, sb[j][2]);
                float yy2 = fminf(yi2, sb[j][3]);
                float ww = fmaxf(xx2 - xx1, 0.0f);
                float hh = fmaxf(yy2 - yy1, 0.0f);
                float inter = ww * hh;
                float iou = inter / (ai + sarea[j] - inter + 1e-9f);
                if (iou > IOU_T) m |= (1ull << jj);
            }
        }
        smask[task] = m;
    }
    __syncthreads();

    if (tid < 64) {
        const int lane = tid;
        u64 kw = 0ull;
        u64 m = (lane < 5) ? smask[lane] : 0ull;
        for (int i = 0; i < K_TOP; ++i) {
            u64 mn = (lane < 5 && (i + 1) < K_TOP) ? smask[(i + 1) * 5 + lane] : 0ull;
            u64 part = m & kw;
            bool sup = (__ballot(part != 0ull) != 0ull);
            if (!sup && lane == (i >> 6)) kw |= (1ull << (i & 63));
            if (lane == 0) skeep[i] = sup ? 0.0f : 1.0f;
            m = mn;
        }
    }
    __syncthreads();
    if (tid < K_TOP)
        out[(size_t)BK * 6 + (size_t)b * K_TOP + tid] = skeep[tid];
}

extern "C" void kernel_launch(void* const* d_in, const int* in_sizes, int n_in,
                              void* d_out, int out_size, void* d_ws, size_t ws_size,
                              hipStream_t stream) {
    const float* logits = (const float*)d_in[0];
    const float* boxes  = (const float*)d_in[1];
    const int*   sizes  = (const int*)d_in[2];
    float* out = (float*)d_out;
    const int B = in_sizes[2] / 2;
    const int C = C_CLS;
    const int Q = in_sizes[0] / (B * C);
    const int N = Q * C;
    const int N4 = N >> 2;

    const size_t need = (size_t)B * CAND_M * 8;
    if (ws_size >= need) {
        u64* cand = (u64*)d_ws;
        scan_sort_kernel<<<B * 2, 512, 0, stream>>>(logits, cand, N, N4);
        nms_fused_kernel<<<B, 1024, 0, stream>>>(cand, boxes, sizes, out, B, Q, C);
    } else {
        rtdetr_post_kernel<<<B, 1024, 0, stream>>>(logits, boxes, sizes, out, B, Q, C);
    }
}

// Round 15
// 59.807 us; speedup vs baseline: 1.0652x; 1.0652x over previous
//
#include <hip/hip_runtime.h>
#include <stdint.h>

#define K_TOP 300
#define C_CLS 80
#define CAND_M 1024
#define THRESH 2.6f
#define IOU_T 0.5f
#define HCAP 512          // candidates per half-image block

typedef unsigned long long u64;
typedef unsigned int u32;

__device__ __forceinline__ u32 f2key(float v) {
    u32 b = __float_as_uint(v);
    return (b & 0x80000000u) ? ~b : (b | 0x80000000u);
}
__device__ __forceinline__ float key2f(u32 k) {
    u32 b = (k & 0x80000000u) ? (k & 0x7FFFFFFFu) : ~k;
    return __uint_as_float(b);
}
__device__ __forceinline__ u64 shfl_xor64(u64 v, int m) {
    u32 lo = (u32)v, hi = (u32)(v >> 32);
    lo = __shfl_xor(lo, m, 64);
    hi = __shfl_xor(hi, m, 64);
    return ((u64)hi << 32) | lo;
}
__device__ __forceinline__ u64 cmpex(u64 v, u64 pv, bool lower, bool dir) {
    bool want_max = (lower == dir);
    bool gt = v > pv;
    return (want_max == gt) ? v : pv;
}

// ---- kernel 1: scan one half-image, collect candidates, sort 512 in-block ----
// Block (img, sub): elements [sub*N/2, (sub+1)*N/2). Direction bit uses the
// GLOBAL element index e = sub*512 + tid, so sub0 ends descending and sub1
// ascending — a ready bitonic sequence for the final k=1024 merge.
__global__ __launch_bounds__(512)
void scan_sort_kernel(const float* __restrict__ logits,
                      u64* __restrict__ cand,
                      int N, int N4) {
    __shared__ u64 lbuf[HCAP];
    __shared__ u32 lcnt;
    const int img = blockIdx.x >> 1;
    const int sub = blockIdx.x & 1;
    const int tid = threadIdx.x;
    if (tid == 0) lcnt = 0;
    __syncthreads();

    const int half4 = N4 >> 1;                     // float4's per half
    const int start4 = sub * half4;
    const int count4 = (sub == 0) ? half4 : (N4 - half4);
    const float4* src = (const float4*)logits + (size_t)img * N4 + start4;
    const u32 idx0 = (u32)start4 << 2;

#define PROC4(v, iu)                                                              \
    {                                                                             \
        float xs[4] = {(v).x, (v).y, (v).z, (v).w};                               \
        _Pragma("unroll")                                                         \
        for (int s = 0; s < 4; ++s) {                                             \
            if (xs[s] > THRESH) {                                                 \
                u32 p = atomicAdd(&lcnt, 1u);                                     \
                if (p < HCAP)                                                     \
                    lbuf[p] = ((u64)f2key(xs[s]) << 32) |                         \
                              (u32)(0xFFFFFFFFu - (idx0 + ((u32)(iu) << 2) + s)); \
            }                                                                     \
        }                                                                         \
    }

    for (int i = tid; i < count4; i += 2048) {
        const int i1 = i + 512, i2 = i + 1024, i3 = i + 1536;
        const bool h1 = i1 < count4, h2 = i2 < count4, h3 = i3 < count4;
        float4 v0 = src[i];
        float4 v1{}, v2{}, v3{};
        if (h1) v1 = src[i1];
        if (h2) v2 = src[i2];
        if (h3) v3 = src[i3];
        PROC4(v0, i);
        if (h1) PROC4(v1, i1);
        if (h2) PROC4(v2, i2);
        if (h3) PROC4(v3, i3);
    }
#undef PROC4
    // scalar tail of the image (N not divisible by 4), sub 1 only
    if (sub == 1) {
        const float* lg = logits + (size_t)img * N;
        for (int i = (N4 << 2) + tid; i < N; i += 512) {
            float x = lg[i];
            if (x > THRESH) {
                u32 p = atomicAdd(&lcnt, 1u);
                if (p < HCAP)
                    lbuf[p] = ((u64)f2key(x) << 32) | (u32)(0xFFFFFFFFu - (u32)i);
            }
        }
    }
    __syncthreads();
    u32 n = lcnt;
    if (n > HCAP) n = HCAP;
    u64 r = ((u32)tid < n) ? lbuf[tid] : 0ull;
    __syncthreads();

    // bitonic sort of this 512-block; dir from global element index e
    const unsigned e = ((unsigned)sub << 9) | (unsigned)tid;
    for (unsigned k = 2; k <= 512; k <<= 1) {
        const bool dir = ((e & k) == 0);
        for (unsigned j = k >> 1; j >= 64; j >>= 1) {
            lbuf[tid] = r;
            __syncthreads();
            u64 p = lbuf[tid ^ j];
            __syncthreads();
            r = cmpex(r, p, (tid & j) == 0, dir);
        }
        unsigned js = ((k >> 1) > 32u) ? 32u : (k >> 1);
        for (unsigned j = js; j >= 1; j >>= 1) {
            u64 p = shfl_xor64(r, (int)j);
            r = cmpex(r, p, (tid & j) == 0, dir);
        }
    }
    cand[(size_t)img * CAND_M + e] = r;
}

// ---- kernel 2: k=1024 merge + decode/outputs + mask build + greedy NMS ----
__global__ __launch_bounds__(1024)
void nms_fused_kernel(const u64* __restrict__ candg,
                      const float* __restrict__ boxes,
                      const int* __restrict__ sizes,
                      float* __restrict__ out,
                      int B, int Q, int C) {
    const int b = blockIdx.x;
    const int tid = threadIdx.x;
    const int BK = B * K_TOP;

    __shared__ u64 sLds[CAND_M];
    __shared__ float4 sbox[K_TOP];
    __shared__ float sar[K_TOP];
    __shared__ u64 smask[K_TOP * 5];   // row-major: [i*5 + w]
    __shared__ u64 skw[5];

    u64 r = candg[(size_t)b * CAND_M + tid];

    // final bitonic merge, k=1024, descending
    for (unsigned j = 512; j >= 64; j >>= 1) {
        sLds[tid] = r;
        __syncthreads();
        u64 p = sLds[tid ^ j];
        __syncthreads();
        r = cmpex(r, p, (tid & j) == 0, true);
    }
    for (unsigned j = 32; j >= 1; j >>= 1) {
        u64 p = shfl_xor64(r, (int)j);
        r = cmpex(r, p, (tid & j) == 0, true);
    }
    // thread tid holds sorted element tid

    // decode + outputs (valid <=> key != 0; real keys always have top bit set)
    if (tid < K_TOP) {
        const int valid = ((u32)(r >> 32)) != 0u;
        const float s0 = (float)sizes[b * 2 + 0];
        const float s1 = (float)sizes[b * 2 + 1];
        u32 key = (u32)(r >> 32);
        u32 idx = 0xFFFFFFFFu - (u32)(r & 0xFFFFFFFFull);
        if (!valid) idx = 0;
        float v = key2f(key);
        float score = valid ? (1.0f / (1.0f + expf(-v))) : 0.0f;
        int q = (int)(idx / (u32)C);
        int lab = (int)idx - q * C;
        float4 bx = ((const float4*)(boxes + ((size_t)b * Q + q) * 4))[0];
        float x1 = (bx.x - 0.5f * bx.z) * s0;
        float y1 = (bx.y - 0.5f * bx.w) * s1;
        float x2 = (bx.x + 0.5f * bx.z) * s0;
        float y2 = (bx.y + 0.5f * bx.w) * s1;
        if (!valid) { x1 = y1 = x2 = y2 = 0.0f; lab = 0; }
        out[(size_t)b * K_TOP + tid] = (float)lab;
        float* ob = out + BK + ((size_t)b * K_TOP + tid) * 4;
        ob[0] = x1; ob[1] = y1; ob[2] = x2; ob[3] = y2;
        out[(size_t)BK * 5 + (size_t)b * K_TOP + tid] = score;
        sbox[tid] = make_float4(x1, y1, x2, y2);
        sar[tid] = (x2 - x1) * (y2 - y1);
    }
    for (int z = tid; z < K_TOP * 5; z += 1024) smask[z] = 0ull;
    __syncthreads();

    // NMS bitmasks: 15 wave-tiles (row-group rg, word w), w <= rg
    {
        const int wv = tid >> 6;
        const int lane = tid & 63;
        if (wv < 15) {
            const int rtab[15] = {0,1,1,2,2,2,3,3,3,3,4,4,4,4,4};
            const int wtab[15] = {0,0,1,0,1,2,0,1,2,3,0,1,2,3,4};
            const int rg = rtab[wv];
            const int w  = wtab[wv];
            const int i  = rg * 64 + lane;
            const int ic = (i < K_TOP) ? i : (K_TOP - 1);
            float4 bi = sbox[ic];
            float ai = sar[ic];
            const int jbase = w << 6;
            int jend = K_TOP - jbase;
            if (jend > 64) jend = 64;
            u64 m = 0ull;
            for (int jj = 0; jj < jend; ++jj) {
                int j = jbase + jj;          // uniform -> LDS broadcast
                float4 bj = sbox[j];
                float aj = sar[j];
                float xx1 = fmaxf(bi.x, bj.x);
                float yy1 = fmaxf(bi.y, bj.y);
                float xx2 = fminf(bi.z, bj.z);
                float yy2 = fminf(bi.w, bj.w);
                float ww = fmaxf(xx2 - xx1, 0.0f);
                float hh = fmaxf(yy2 - yy1, 0.0f);
                float inter = ww * hh;
                float iou = inter / (ai + aj - inter + 1e-9f);
                if (iou > IOU_T && j < i) m |= (1ull << jj);
            }
            if (i < K_TOP) smask[i * 5 + w] = m;
        }
    }
    __syncthreads();

    // greedy scan, software-pipelined 4-row lookahead (wave 0)
    if (tid < 64) {
        const int lane = tid;
        const bool act = (lane < 5);
        u64 kw = 0ull;
#define LDM(row) ((act && (row) < K_TOP) ? smask[(row) * 5 + lane] : 0ull)
#define GSTEP(mrow, ii)                                                   \
        {                                                                 \
            u64 part = (mrow) & kw;                                       \
            bool sup = (__ballot(part != 0ull) != 0ull);                  \
            if (!sup && lane == ((ii) >> 6)) kw |= (1ull << ((ii) & 63)); \
        }
        u64 n0 = LDM(0), n1 = LDM(1), n2 = LDM(2), n3 = LDM(3);
        for (int c = 0; c < K_TOP / 4; ++c) {
            const int base = c * 4;
            u64 p0 = LDM(base + 4);
            u64 p1 = LDM(base + 5);
            u64 p2 = LDM(base + 6);
            u64 p3 = LDM(base + 7);
            GSTEP(n0, base + 0);
            GSTEP(n1, base + 1);
            GSTEP(n2, base + 2);
            GSTEP(n3, base + 3);
            n0 = p0; n1 = p1; n2 = p2; n3 = p3;
        }
#undef LDM
#undef GSTEP
        if (act) skw[lane] = kw;
    }
    __syncthreads();
    if (tid < K_TOP) {
        u32 keep = (u32)((skw[tid >> 6] >> (tid & 63)) & 1ull);
        out[(size_t)BK * 6 + (size_t)b * K_TOP + tid] = (float)keep;
    }
}

// ---------------- fallback monolithic (proven round-1) ----------------

__global__ __launch_bounds__(1024)
void rtdetr_post_kernel(const float* __restrict__ logits,
                        const float* __restrict__ boxes,
                        const int* __restrict__ sizes,
                        float* __restrict__ out,
                        int B, int Q, int C) {
    const int b = blockIdx.x;
    const int tid = threadIdx.x;
    const int bd = blockDim.x;
    const int N = Q * C;
    const int BK = B * K_TOP;

    __shared__ u64 cand[CAND_M];
    __shared__ u32 s_ncand;
    __shared__ float sb[K_TOP][4];
    __shared__ float sarea[K_TOP];
    __shared__ u64 smask[K_TOP * 5];
    __shared__ float skeep[K_TOP];

    if (tid == 0) s_ncand = 0;
    __syncthreads();

    const float* lg = logits + (size_t)b * N;
    const int nv = N >> 2;
    const float4* lg4 = (const float4*)lg;
    for (int i = tid; i < nv; i += bd) {
        float4 v = lg4[i];
        const int base = i * 4;
        float xs[4] = {v.x, v.y, v.z, v.w};
#pragma unroll
        for (int s = 0; s < 4; ++s) {
            float x = xs[s];
            if (x > THRESH) {
                u32 pos = atomicAdd(&s_ncand, 1u);
                if (pos < CAND_M)
                    cand[pos] = ((u64)f2key(x) << 32) | (u32)(0xFFFFFFFFu - (u32)(base + s));
            }
        }
    }
    __syncthreads();
    u32 ncand = s_ncand;
    if (ncand > CAND_M) ncand = CAND_M;
    for (int i = tid; i < CAND_M; i += bd)
        if (i >= (int)ncand) cand[i] = 0ull;
    __syncthreads();

    for (unsigned k = 2; k <= CAND_M; k <<= 1) {
        for (unsigned j = k >> 1; j > 0; j >>= 1) {
            for (unsigned t = tid; t < CAND_M; t += bd) {
                unsigned ixj = t ^ j;
                if (ixj > t) {
                    u64 a = cand[t], bb = cand[ixj];
                    bool sw = ((t & k) == 0) ? (a < bb) : (a > bb);
                    if (sw) { cand[t] = bb; cand[ixj] = a; }
                }
            }
            __syncthreads();
        }
    }

    const float s0 = (float)sizes[b * 2 + 0];
    const float s1 = (float)sizes[b * 2 + 1];
    if (tid < K_TOP) {
        u64 e = cand[tid];
        const int valid = (tid < (int)ncand);
        u32 key = (u32)(e >> 32);
        u32 idx = 0xFFFFFFFFu - (u32)(e & 0xFFFFFFFFull);
        if (!valid) idx = 0;
        float v = key2f(key);
        float score = valid ? (1.0f / (1.0f + expf(-v))) : 0.0f;
        int q = (int)(idx / (u32)C);
        int lab = (int)idx - q * C;
        float4 bx = ((const float4*)(boxes + ((size_t)b * Q + q) * 4))[0];
        float x1 = (bx.x - 0.5f * bx.z) * s0;
        float y1 = (bx.y - 0.5f * bx.w) * s1;
        float x2 = (bx.x + 0.5f * bx.z) * s0;
        float y2 = (bx.y + 0.5f * bx.w) * s1;
        if (!valid) { x1 = y1 = x2 = y2 = 0.0f; lab = 0; }
        out[(size_t)b * K_TOP + tid] = (float)lab;
        float* ob = out + BK + ((size_t)b * K_TOP + tid) * 4;
        ob[0] = x1; ob[1] = y1; ob[2] = x2; ob[3] = y2;
        out[(size_t)BK * 5 + (size_t)b * K_TOP + tid] = score;
        sb[tid][0] = x1; sb[tid][1] = y1; sb[tid][2] = x2; sb[tid][3] = y2;
        sarea[tid] = (x2 - x1) * (y2 - y1);
    }
    __syncthreads();

    for (int task = tid; task < K_TOP * 5; task += bd) {
        int i = task / 5;
        int w = task - i * 5;
        int jbase = w * 64;
        u64 m = 0ull;
        int jend = i - jbase;
        if (jend > 64) jend = 64;
        if (jend > 0) {
            float xi1 = sb[i][0], yi1 = sb[i][1], xi2 = sb[i][2], yi2 = sb[i][3];
            float ai = sarea[i];
            for (int jj = 0; jj < jend; ++jj) {
                int j = jbase + jj;
                float xx1 = fmaxf(xi1, sb[j][0]);
                float yy1 = fmaxf(yi1, sb[j][1]);
                float xx2 = fminf(xi2, sb[j][2]);
                float yy2 = fminf(yi2, sb[j][3]);
                float ww = fmaxf(xx2 - xx1, 0.0f);
                float hh = fmaxf(yy2 - yy1, 0.0f);
                float inter = ww * hh;
                float iou = inter / (ai + sarea[j] - inter + 1e-9f);
                if (iou > IOU_T) m |= (1ull << jj);
            }
        }
        smask[task] = m;
    }
    __syncthreads();

    if (tid < 64) {
        const int lane = tid;
        u64 kw = 0ull;
        u64 m = (lane < 5) ? smask[lane] : 0ull;
        for (int i = 0; i < K_TOP; ++i) {
            u64 mn = (lane < 5 && (i + 1) < K_TOP) ? smask[(i + 1) * 5 + lane] : 0ull;
            u64 part = m & kw;
            bool sup = (__ballot(part != 0ull) != 0ull);
            if (!sup && lane == (i >> 6)) kw |= (1ull << (i & 63));
            if (lane == 0) skeep[i] = sup ? 0.0f : 1.0f;
            m = mn;
        }
    }
    __syncthreads();
    if (tid < K_TOP)
        out[(size_t)BK * 6 + (size_t)b * K_TOP + tid] = skeep[tid];
}

extern "C" void kernel_launch(void* const* d_in, const int* in_sizes, int n_in,
                              void* d_out, int out_size, void* d_ws, size_t ws_size,
                              hipStream_t stream) {
    const float* logits = (const float*)d_in[0];
    const float* boxes  = (const float*)d_in[1];
    const int*   sizes  = (const int*)d_in[2];
    float* out = (float*)d_out;
    const int B = in_sizes[2] / 2;
    const int C = C_CLS;
    const int Q = in_sizes[0] / (B * C);
    const int N = Q * C;
    const int N4 = N >> 2;

    const size_t need = (size_t)B * CAND_M * 8;
    if (ws_size >= need) {
        u64* cand = (u64*)d_ws;
        scan_sort_kernel<<<B * 2, 512, 0, stream>>>(logits, cand, N, N4);
        nms_fused_kernel<<<B, 1024, 0, stream>>>(cand, boxes, sizes, out, B, Q, C);
    } else {
        rtdetr_post_kernel<<<B, 1024, 0, stream>>>(logits, boxes, sizes, out, B, Q, C);
    }
}